// Round 12
// baseline (223.195 us; speedup 1.0000x reference)
//
#include <hip/hip_runtime.h>
#include <math.h>

// Sinkhorn-divergence triplet loss (geomloss-style), MI355X.
// R12: length-masked work skipping. Padding is tail-contiguous (mask =
// arange<len), padded rows contribute EXACTLY zero (loga=NEG kills them; their
// f never consumed). Guards at 16-row quad granularity (wave-uniform, static
// reg indexing preserved); potf2 init SENT / potentials init 0 so overshoot
// reads are finite and exp-flush to 0. Cost kernels stage zeros for padded
// rows (C stays finite) and skip MFMA per wave / col-tile.
// Base: R11 exact 2-pass cached-x LSE, MFMA split-bf16 costs, native v_exp.
// Launch-bounds law: never pass arg2 (VGPR cap = 256/arg2, measured R3/R4).

namespace {
constexpr int NB = 128, NL = 128, ND = 300, NK = 10, NR = 50, NITER = 20;
constexpr float LOG2E   = 1.4426950408889634f;
constexpr float EPS     = 0.0025f;                  // blur^p = 0.05^2
constexpr float CSCALE  = 0.5f * LOG2E / EPS;       // squared-dist -> log2-domain cost
constexpr float VSCALE  = EPS * 0.6931471805599453f; // log2-potential -> nat (eps*ln2)
constexpr float LOG2_50 = 5.6438561897747395f;      // log2(50)
constexpr float NEGL2   = -1.442695e9f;             // -1e9 * log2e
constexpr float SENT    = -3.0e38f;                 // sentinel (exp2 -> 0)
constexpr int KCH = 10;                              // K chunks of 32
constexpr int PIT = 40;                              // LDS pitch in shorts
}

typedef __attribute__((ext_vector_type(8))) short bf16x8;
typedef __attribute__((ext_vector_type(4))) float f32x4;

__device__ inline float ex2(float x) { return __builtin_amdgcn_exp2f(x); }
__device__ inline float lg2(float x) { return __builtin_amdgcn_logf(x); }
__device__ inline f32x4 vmax4(f32x4 a, f32x4 b) {
  f32x4 r;
  r[0] = fmaxf(a[0], b[0]); r[1] = fmaxf(a[1], b[1]);
  r[2] = fmaxf(a[2], b[2]); r[3] = fmaxf(a[3], b[3]);
  return r;
}
__device__ inline f32x4 vexp4(f32x4 x) {
  f32x4 r;
  r[0] = ex2(x[0]); r[1] = ex2(x[1]); r[2] = ex2(x[2]); r[3] = ex2(x[3]);
  return r;
}

__device__ inline unsigned short f2bf_rn(float x) {
  unsigned int u = __float_as_uint(x);
  unsigned int r = (u + 0x7fffu + ((u >> 16) & 1u)) >> 16;
  return (unsigned short)r;
}
__device__ inline float bf2f(unsigned short h) {
  return __uint_as_float((unsigned int)h << 16);
}

// ---------------------------------------------------------------- prep
__global__ void prep_kernel(const float* __restrict__ anchor,
                            const float* __restrict__ weight,
                            const float* __restrict__ t0,
                            const int* __restrict__ len,
                            float* __restrict__ na, float* __restrict__ nt,
                            float* __restrict__ lw2) {
  int wid  = (blockIdx.x * blockDim.x + threadIdx.x) >> 6;
  int lane = threadIdx.x & 63;
  const int nA = NB * NL;
  const int total = nA + NK * NR;
  if (wid >= total) return;
  const float* src = (wid < nA) ? (anchor + (size_t)wid * ND)
                                : (t0 + (size_t)(wid - nA) * ND);
  float s = 0.f;
  for (int d = lane; d < ND; d += 64) { float v = src[d]; s += v * v; }
  #pragma unroll
  for (int off = 32; off; off >>= 1) s += __shfl_xor(s, off);
  if (lane == 0) { if (wid < nA) na[wid] = s; else nt[wid - nA] = s; }
  if (wid < nA && lane == 1) {
    int b = wid >> 7, l = wid & 127;
    float w = weight[wid];
    lw2[wid] = (l < len[b]) ? log2f(fmaxf(w, 1e-12f)) : NEGL2;
  }
}

// ---------------------------------------------------------------- staging helper
__device__ inline void stage8(const float* __restrict__ src, bool rowvalid,
                              int kg, short* __restrict__ Hs, short* __restrict__ Ls,
                              int lofs) {
  float xv[8];
  if (rowvalid && kg + 8 <= ND) {
    float4 u = *(const float4*)(src + kg);
    float4 v = *(const float4*)(src + kg + 4);
    xv[0]=u.x; xv[1]=u.y; xv[2]=u.z; xv[3]=u.w;
    xv[4]=v.x; xv[5]=v.y; xv[6]=v.z; xv[7]=v.w;
  } else {
    #pragma unroll
    for (int e = 0; e < 8; ++e)
      xv[e] = (rowvalid && kg + e < ND) ? src[kg + e] : 0.f;
  }
  bf16x8 hv, lv;
  #pragma unroll
  for (int e = 0; e < 8; ++e) {
    unsigned short h = f2bf_rn(xv[e]);
    float hf = bf2f(h);
    unsigned short l = f2bf_rn(xv[e] - hf);
    hv[e] = (short)h; lv[e] = (short)l;
  }
  *(bf16x8*)(Hs + lofs) = hv;
  *(bf16x8*)(Ls + lofs) = lv;
}

// ---------------------------------------------------------------- cost MFMA (ab / tt)
// len != nullptr (mode 0): rows >= len[blockIdx.x] staged as zeros, MFMA
// skipped per wave. C for padded rows stays finite (acc=0 -> (nx+ny)*CSCALE).
__global__ __launch_bounds__(512)
void cost_mfma(const float* __restrict__ X, const float* __restrict__ Y,
               const float* __restrict__ NX, const float* __restrict__ NY,
               const int* __restrict__ len,
               float* __restrict__ C, int nX, int nY, int mode) {
  __shared__ __align__(16) short Ah[128 * PIT], Al[128 * PIT];
  __shared__ __align__(16) short Bh[128 * PIT], Bl[128 * PIT];

  const int t = threadIdx.x;
  const int i0 = blockIdx.x * 128, j0 = blockIdx.y * 128;
  const int Lb = len ? len[blockIdx.x] : (1 << 30);
  const int srow = t >> 2, skq = t & 3, kloc = skq * 8;
  const int lofs = srow * PIT + kloc;
  const bool avalid = (i0 + srow) < nX && srow < Lb;
  const bool bvalid = (j0 + srow) < nY;
  const float* aro = X + (size_t)(i0 + srow) * ND;
  const float* bro = Y + (size_t)(j0 + srow) * ND;

  const int lane = t & 63, w = t >> 6;
  const int fr = lane & 15, fo = (lane >> 4) * 8;
  const int aofs = (w * 16 + fr) * PIT + fo;
  const bool wact = (w * 16 < Lb);

  f32x4 acc[8];
  #pragma unroll
  for (int cc = 0; cc < 8; ++cc) acc[cc] = (f32x4){0.f, 0.f, 0.f, 0.f};

  for (int c = 0; c < KCH; ++c) {
    int kg = c * 32 + kloc;
    stage8(aro, avalid, kg, Ah, Al, lofs);
    stage8(bro, bvalid, kg, Bh, Bl, lofs);
    __syncthreads();

    if (wact) {
      bf16x8 ah = *(const bf16x8*)(Ah + aofs);
      bf16x8 al = *(const bf16x8*)(Al + aofs);
      #pragma unroll
      for (int cc = 0; cc < 8; ++cc) {
        int bofs = (cc * 16 + fr) * PIT + fo;
        bf16x8 bh = *(const bf16x8*)(Bh + bofs);
        bf16x8 bl = *(const bf16x8*)(Bl + bofs);
        acc[cc] = __builtin_amdgcn_mfma_f32_16x16x32_bf16(ah, bh, acc[cc], 0, 0, 0);
        acc[cc] = __builtin_amdgcn_mfma_f32_16x16x32_bf16(ah, bl, acc[cc], 0, 0, 0);
        acc[cc] = __builtin_amdgcn_mfma_f32_16x16x32_bf16(al, bh, acc[cc], 0, 0, 0);
      }
    }
    __syncthreads();
  }

  #pragma unroll
  for (int cc = 0; cc < 8; ++cc) {
    int gj = j0 + cc * 16 + fr;
    if (gj >= nY) continue;
    float ny = NY[gj];
    #pragma unroll
    for (int reg = 0; reg < 4; ++reg) {
      int gi = i0 + w * 16 + (lane >> 4) * 4 + reg;
      if (gi >= nX) continue;
      float sq = NX[gi] + ny - 2.f * acc[cc][reg];
      float cv = fmaxf(sq, 0.f) * CSCALE;
      if (mode == 0) {
        int k = gj / 50, jj = gj - k * 50;
        C[((size_t)((gi >> 7) * NK + k)) * (NL * NR) + (gi & 127) * NR + jj] = cv;
      } else {
        int ki = gi / 50, ii = gi - ki * 50;
        int kj = gj / 50, jj = gj - kj * 50;
        C[((size_t)(ki * NK + kj)) * (NR * NR) + ii * NR + jj] = cv;
      }
    }
  }
}

// ---------------------------------------------------------------- cost MFMA (aa)
__global__ __launch_bounds__(512)
void cost_mfma_aa(const float* __restrict__ X, const float* __restrict__ NX,
                  const int* __restrict__ len, float* __restrict__ C) {
  __shared__ __align__(16) short Ah[128 * PIT], Al[128 * PIT];

  const int t = threadIdx.x, b = blockIdx.x;
  const int Lb = len[b];
  const int srow = t >> 2, skq = t & 3, kloc = skq * 8;
  const int lofs = srow * PIT + kloc;
  const float* aro = X + (size_t)(b * NL + srow) * ND;
  const bool avalid = srow < Lb;

  const int lane = t & 63, w = t >> 6;
  const int fr = lane & 15, fo = (lane >> 4) * 8;
  const int aofs = (w * 16 + fr) * PIT + fo;
  const bool wact = (w * 16 < Lb);

  f32x4 acc[8];
  #pragma unroll
  for (int cc = 0; cc < 8; ++cc) acc[cc] = (f32x4){0.f, 0.f, 0.f, 0.f};

  for (int c = 0; c < KCH; ++c) {
    stage8(aro, avalid, c * 32 + kloc, Ah, Al, lofs);
    __syncthreads();

    if (wact) {
      bf16x8 ah = *(const bf16x8*)(Ah + aofs);
      bf16x8 al = *(const bf16x8*)(Al + aofs);
      #pragma unroll
      for (int cc = 0; cc < 8; ++cc) {
        if (cc * 16 < Lb) {
          int bofs = (cc * 16 + fr) * PIT + fo;
          bf16x8 bh = *(const bf16x8*)(Ah + bofs);
          bf16x8 bl = *(const bf16x8*)(Al + bofs);
          acc[cc] = __builtin_amdgcn_mfma_f32_16x16x32_bf16(ah, bh, acc[cc], 0, 0, 0);
          acc[cc] = __builtin_amdgcn_mfma_f32_16x16x32_bf16(ah, bl, acc[cc], 0, 0, 0);
          acc[cc] = __builtin_amdgcn_mfma_f32_16x16x32_bf16(al, bh, acc[cc], 0, 0, 0);
        }
      }
    }
    __syncthreads();
  }

  const float* nb = NX + b * NL;
  float* Cb = C + (size_t)b * (NL * NL);
  #pragma unroll
  for (int cc = 0; cc < 8; ++cc) {
    int gj = cc * 16 + fr;
    float ny = nb[gj];
    #pragma unroll
    for (int reg = 0; reg < 4; ++reg) {
      int gi = w * 16 + (lane >> 4) * 4 + reg;
      float sq = nb[gi] + ny - 2.f * acc[cc][reg];
      Cb[(size_t)gi * NL + gj] = fmaxf(sq, 0.f) * CSCALE;
    }
  }
}

// ---------------------------------------------------------------- sinkhorn ab + tt (fused launch)
__global__ __launch_bounds__(256)
void sinkhorn_abtt(const float* __restrict__ Cab, const float* __restrict__ Ctt,
                   const float* __restrict__ lw2, const float* __restrict__ weight,
                   const int* __restrict__ len,
                   float* __restrict__ oab, float* __restrict__ ott) {
  __shared__ __align__(16) float smem[444];
  const int t = threadIdx.x;

  if (blockIdx.x < NB * NK) {
    // ------------------------------ ab body (128x50), rows >= Lb skipped
    float* g2    = smem;                 // 56 (50 real + 6 SENT pads)
    float* f2    = smem + 56;            // 128
    float* potf2 = smem + 184;           // 128 (16B-aligned)
    float* la2s  = smem + 312;           // 128
    float* red   = smem + 440;           // 4
    int p = blockIdx.x, b = p / NK;
    const int Lb = len[b];
    const float* Cp = Cab + (size_t)p * (NL * NR);
    if (t < NL) { la2s[t] = lw2[b * NL + t]; f2[t] = 0.f; potf2[t] = SENT; }
    if (t < NR) g2[t] = 0.f;
    else if (t < 56) g2[t] = SENT;

    const int rf = t >> 1, sf = t & 1;
    const bool fact = (rf < Lb);
    f32x4 Crow4[7];                      // -C row fragment (immutable)
    if (fact) {
      const float* rp = Cp + rf * NR;
      #pragma unroll
      for (int q = 0; q < 7; ++q)
        #pragma unroll
        for (int e = 0; e < 4; ++e) {
          int col = sf * 28 + q * 4 + e;
          Crow4[q][e] = (col < NR) ? -rp[col] : 0.f;
        }
    }
    const int cc = t >> 2, sc = t & 3;
    f32x4 Ccol4[8];                      // -C col fragment, quad-interleaved rows
    if (t < 200) {
      #pragma unroll
      for (int q = 0; q < 8; ++q) {
        if (16 * q < Lb) {
          #pragma unroll
          for (int e = 0; e < 4; ++e)
            Ccol4[q][e] = -Cp[(16 * q + 4 * sc + e) * NR + cc];
        }
      }
    }
    __syncthreads();

    const f32x4* g4base = (const f32x4*)(g2 + sf * 28);

    for (int it = 0; it < NITER; ++it) {
      // ---- f update (valid rows only)
      if (fact) {
        f32x4 x[7];
        f32x4 m4 = {SENT, SENT, SENT, SENT};
        #pragma unroll
        for (int q = 0; q < 7; ++q) {
          x[q] = g4base[q] + Crow4[q];
          m4 = vmax4(m4, x[q]);
        }
        float mx = fmaxf(fmaxf(m4[0], m4[1]), fmaxf(m4[2], m4[3]));
        mx = fmaxf(mx, __shfl_xor(mx, 1));
        f32x4 s4 = {0.f, 0.f, 0.f, 0.f};
        #pragma unroll
        for (int q = 0; q < 7; ++q) s4 += vexp4(x[q] - mx);
        float s = (s4[0] + s4[1]) + (s4[2] + s4[3]);
        s += __shfl_xor(s, 1);
        if (sf == 0) {
          float fv = LOG2_50 - mx - lg2(s);
          f2[rf] = fv; potf2[rf] = la2s[rf] + fv;
        }
      }
      __syncthreads();
      // ---- g update: quad-interleaved row groups, skip groups >= Lb
      if (t < 200) {
        f32x4 x[8];
        f32x4 m4 = {SENT, SENT, SENT, SENT};
        #pragma unroll
        for (int q = 0; q < 8; ++q) {
          if (16 * q < Lb) {
            x[q] = *(const f32x4*)(potf2 + 16 * q + 4 * sc) + Ccol4[q];
            m4 = vmax4(m4, x[q]);
          }
        }
        float mx = fmaxf(fmaxf(m4[0], m4[1]), fmaxf(m4[2], m4[3]));
        mx = fmaxf(mx, __shfl_xor(mx, 1));
        mx = fmaxf(mx, __shfl_xor(mx, 2));
        f32x4 s4 = {0.f, 0.f, 0.f, 0.f};
        #pragma unroll
        for (int q = 0; q < 8; ++q) {
          if (16 * q < Lb) s4 += vexp4(x[q] - mx);
        }
        float s = (s4[0] + s4[1]) + (s4[2] + s4[3]);
        s += __shfl_xor(s, 1);
        s += __shfl_xor(s, 2);
        if (sc == 0) g2[cc] = -(mx + lg2(s));
      }
      __syncthreads();
    }

    float acc = 0.f;
    if (t < NL) acc = weight[b * NL + t] * f2[t];
    else if (t < NL + NR) acc = g2[t - NL] * (1.0f / NR);
    #pragma unroll
    for (int off = 32; off; off >>= 1) acc += __shfl_xor(acc, off);
    if ((t & 63) == 0) red[t >> 6] = acc;
    __syncthreads();
    if (t == 0) oab[p] = VSCALE * (red[0] + red[1] + red[2] + red[3]);

  } else {
    // ------------------------------ tt body (50x50, both uniform 1/50)
    float* f2 = smem;                    // 50
    float* g2 = smem + 56;               // 50
    float* red = smem + 112;             // 4
    int p = blockIdx.x - NB * NK;
    const float* Cp = Ctt + (size_t)p * (NR * NR);
    if (t < NR) g2[t] = 0.f;

    const int r = t >> 2, sub = t & 3;
    const bool act = (t < 200);
    float Crowb[13], Ccolb[13];
    if (act) {
      #pragma unroll
      for (int j = 0; j < 13; ++j) {
        int idx = sub + 4 * j;
        Crowb[j] = (idx < NR) ? -Cp[r * NR + idx] : SENT;
        Ccolb[j] = (idx < NR) ? -Cp[idx * NR + r] : SENT;
      }
    }
    __syncthreads();

    for (int it = 0; it < NITER; ++it) {
      if (act) {
        float x[13];
        float m0 = SENT, m1 = SENT;
        #pragma unroll
        for (int j = 0; j < 12; j += 2) {
          x[j]     = g2[sub + 4 * j]       + Crowb[j];
          x[j + 1] = g2[sub + 4 * (j + 1)] + Crowb[j + 1];
          m0 = fmaxf(m0, x[j]); m1 = fmaxf(m1, x[j + 1]);
        }
        { int i0 = sub + 48; x[12] = ((i0 < NR) ? g2[i0] : 0.f) + Crowb[12];
          m0 = fmaxf(m0, x[12]); }
        float mx = fmaxf(m0, m1);
        mx = fmaxf(mx, __shfl_xor(mx, 1));
        mx = fmaxf(mx, __shfl_xor(mx, 2));
        float s0 = 0.f, s1 = 0.f;
        #pragma unroll
        for (int j = 0; j < 12; j += 2) {
          s0 += ex2(x[j] - mx); s1 += ex2(x[j + 1] - mx);
        }
        s0 += ex2(x[12] - mx);
        float s = s0 + s1;
        s += __shfl_xor(s, 1);
        s += __shfl_xor(s, 2);
        if (sub == 0) f2[r] = LOG2_50 - mx - lg2(s);
      }
      __syncthreads();
      if (act) {
        float x[13];
        float m0 = SENT, m1 = SENT;
        #pragma unroll
        for (int j = 0; j < 12; j += 2) {
          x[j]     = f2[sub + 4 * j]       + Ccolb[j];
          x[j + 1] = f2[sub + 4 * (j + 1)] + Ccolb[j + 1];
          m0 = fmaxf(m0, x[j]); m1 = fmaxf(m1, x[j + 1]);
        }
        { int i0 = sub + 48; x[12] = ((i0 < NR) ? f2[i0] : 0.f) + Ccolb[12];
          m0 = fmaxf(m0, x[12]); }
        float mx = fmaxf(m0, m1);
        mx = fmaxf(mx, __shfl_xor(mx, 1));
        mx = fmaxf(mx, __shfl_xor(mx, 2));
        float s0 = 0.f, s1 = 0.f;
        #pragma unroll
        for (int j = 0; j < 12; j += 2) {
          s0 += ex2(x[j] - mx); s1 += ex2(x[j + 1] - mx);
        }
        s0 += ex2(x[12] - mx);
        float s = s0 + s1;
        s += __shfl_xor(s, 1);
        s += __shfl_xor(s, 2);
        if (sub == 0) g2[r] = LOG2_50 - mx - lg2(s);
      }
      __syncthreads();
    }

    float acc = 0.f;
    if (t < NR) acc = f2[t] + g2[t];
    #pragma unroll
    for (int off = 32; off; off >>= 1) acc += __shfl_xor(acc, off);
    if ((t & 63) == 0) red[t >> 6] = acc;
    __syncthreads();
    if (t == 0) ott[p] = VSCALE * (1.0f / NR) * (red[0] + red[1] + red[2] + red[3]);
  }
}

// ---------------------------------------------------------------- sinkhorn aa
// Symmetric C, equal marginals, immutable folded cost (la2 - C); rows >= Lb
// skipped; col quads interleaved (cols 16q+4sub..+3), groups >= Lb skipped.
__global__ __launch_bounds__(512)
void sinkhorn_aa(const float* __restrict__ Cg, const float* __restrict__ lw2,
                 const float* __restrict__ weight, const int* __restrict__ len,
                 float* __restrict__ ot) {
  __shared__ __align__(16) float pF[NL];
  __shared__ __align__(16) float pG[NL];
  __shared__ float red[8];
  int b = blockIdx.x, t = threadIdx.x;
  const int Lb = len[b];
  int r = t >> 2, sub = t & 3;
  const bool ract = (r < Lb);
  const float* Cr = Cg + (size_t)b * (NL * NL) + (size_t)r * NL;
  const float* lp = lw2 + b * NL;
  f32x4 Cr4[8];                          // la2[col] - C[r][col], quad-interleaved
  if (ract) {
    #pragma unroll
    for (int q = 0; q < 8; ++q) {
      if (16 * q < Lb) {
        int c0 = 16 * q + 4 * sub;
        float4 cv = *(const float4*)(Cr + c0);
        float4 lv = *(const float4*)(lp + c0);
        Cr4[q] = (f32x4){lv.x - cv.x, lv.y - cv.y, lv.z - cv.z, lv.w - cv.w};
      }
    }
  }
  if (t < NL) { pG[t] = 0.f; pF[t] = 0.f; }
  __syncthreads();

  for (int it = 0; it < NITER; ++it) {
    // ---- f = T(g)
    if (ract) {
      f32x4 x[8];
      f32x4 m4 = {SENT, SENT, SENT, SENT};
      #pragma unroll
      for (int q = 0; q < 8; ++q) {
        if (16 * q < Lb) {
          x[q] = *(const f32x4*)(pG + 16 * q + 4 * sub) + Cr4[q];
          m4 = vmax4(m4, x[q]);
        }
      }
      float mx = fmaxf(fmaxf(m4[0], m4[1]), fmaxf(m4[2], m4[3]));
      mx = fmaxf(mx, __shfl_xor(mx, 1));
      mx = fmaxf(mx, __shfl_xor(mx, 2));
      f32x4 s4 = {0.f, 0.f, 0.f, 0.f};
      #pragma unroll
      for (int q = 0; q < 8; ++q) {
        if (16 * q < Lb) s4 += vexp4(x[q] - mx);
      }
      float s = (s4[0] + s4[1]) + (s4[2] + s4[3]);
      s += __shfl_xor(s, 1);
      s += __shfl_xor(s, 2);
      if (sub == 0) pF[r] = -(mx + lg2(s));
    }
    __syncthreads();
    // ---- g = T(f)
    if (ract) {
      f32x4 x[8];
      f32x4 m4 = {SENT, SENT, SENT, SENT};
      #pragma unroll
      for (int q = 0; q < 8; ++q) {
        if (16 * q < Lb) {
          x[q] = *(const f32x4*)(pF + 16 * q + 4 * sub) + Cr4[q];
          m4 = vmax4(m4, x[q]);
        }
      }
      float mx = fmaxf(fmaxf(m4[0], m4[1]), fmaxf(m4[2], m4[3]));
      mx = fmaxf(mx, __shfl_xor(mx, 1));
      mx = fmaxf(mx, __shfl_xor(mx, 2));
      f32x4 s4 = {0.f, 0.f, 0.f, 0.f};
      #pragma unroll
      for (int q = 0; q < 8; ++q) {
        if (16 * q < Lb) s4 += vexp4(x[q] - mx);
      }
      float s = (s4[0] + s4[1]) + (s4[2] + s4[3]);
      s += __shfl_xor(s, 1);
      s += __shfl_xor(s, 2);
      if (sub == 0) pG[r] = -(mx + lg2(s));
    }
    __syncthreads();
  }

  float acc = 0.f;
  if (t < NL) acc = weight[b * NL + t] * (pF[t] + pG[t]);
  #pragma unroll
  for (int off = 32; off; off >>= 1) acc += __shfl_xor(acc, off);
  if ((t & 63) == 0) red[t >> 6] = acc;
  __syncthreads();
  if (t == 0) {
    float v = 0.f;
    #pragma unroll
    for (int i = 0; i < 8; ++i) v += red[i];
    ot[b] = VSCALE * v;
  }
}

// ---------------------------------------------------------------- finalize
__global__ void finalize_kernel(const float* __restrict__ oab, const float* __restrict__ oaa,
                                const float* __restrict__ ott, const int* __restrict__ grade,
                                float* __restrict__ out) {
  __shared__ float selft[NK];
  __shared__ float redL[4], redD[4];
  int t = threadIdx.x;
  if (t < NK) selft[t] = ott[t * NK + t];
  __syncthreads();
  float dpart = (t < NK * NK) ? ott[t] : 0.f;
  float lpart = 0.f;
  if (t < NB) {
    int g = grade[t];
    float oa = oaa[t];
    float dpos = oab[t * NK + g] - 0.5f * (oa + selft[g]);
    float s = 0.f;
    #pragma unroll
    for (int k = 0; k < NK; ++k) {
      float dk = oab[t * NK + k] - 0.5f * (oa + selft[k]);
      s += fmaxf(dpos - dk + 10.0f, 0.0f);
    }
    lpart = s - 10.0f;
  }
  #pragma unroll
  for (int off = 32; off; off >>= 1) {
    dpart += __shfl_xor(dpart, off);
    lpart += __shfl_xor(lpart, off);
  }
  if ((t & 63) == 0) { redD[t >> 6] = dpart; redL[t >> 6] = lpart; }
  __syncthreads();
  if (t == 0) {
    float ds = 0.f, ls = 0.f;
    #pragma unroll
    for (int i = 0; i < 4; ++i) { ds += redD[i]; ls += redL[i]; }
    float ss = 0.f;
    #pragma unroll
    for (int k = 0; k < NK; ++k) ss += selft[k];
    float dis = ds - (float)NK * ss;
    out[0] = ls / (float)NB - dis * 0.01f;
  }
}

// ---------------------------------------------------------------- launch
extern "C" void kernel_launch(void* const* d_in, const int* in_sizes, int n_in,
                              void* d_out, int out_size, void* d_ws, size_t ws_size,
                              hipStream_t stream) {
  (void)in_sizes; (void)n_in; (void)out_size; (void)ws_size;
  const float* anchor = (const float*)d_in[0];
  const float* weight = (const float*)d_in[1];
  const float* t0     = (const float*)d_in[2];
  const int*   len    = (const int*)d_in[3];
  const int*   grade  = (const int*)d_in[4];
  float* out = (float*)d_out;

  float* ws  = (float*)d_ws;
  float* Cab = ws;                                    // 819200
  float* Caa = Cab + (size_t)NB * NK * NL * NR;       // 2097152
  float* Ctt = Caa + (size_t)NB * NL * NL;            // 250000
  float* na  = Ctt + (size_t)NK * NK * NR * NR;       // 16384
  float* nt  = na + NB * NL;                          // 500
  float* lw2 = nt + NK * NR;                          // 16384
  float* oab = lw2 + NB * NL;                         // 1280
  float* oaa = oab + NB * NK;                         // 128
  float* ott = oaa + NB;                              // 100

  prep_kernel<<<(NB * NL + NK * NR) / 4, 256, 0, stream>>>(anchor, weight, t0, len, na, nt, lw2);
  cost_mfma<<<dim3(128, 4), 512, 0, stream>>>(anchor, t0, na, nt, len, Cab,
                                              NB * NL, NK * NR, 0);
  cost_mfma<<<dim3(4, 4), 512, 0, stream>>>(t0, t0, nt, nt, nullptr, Ctt,
                                            NK * NR, NK * NR, 2);
  cost_mfma_aa<<<NB, 512, 0, stream>>>(anchor, na, len, Caa);

  sinkhorn_abtt<<<NB * NK + NK * NK, 256, 0, stream>>>(Cab, Ctt, lw2, weight, len, oab, ott);
  sinkhorn_aa<<<NB, 512, 0, stream>>>(Caa, lw2, weight, len, oaa);
  finalize_kernel<<<1, 256, 0, stream>>>(oab, oaa, ott, grade, out);
}

// Round 13
// 165.311 us; speedup vs baseline: 1.3502x; 1.3502x over previous
//
#include <hip/hip_runtime.h>
#include <math.h>

// Sinkhorn-divergence triplet loss (geomloss-style), MI355X.
// R13: R12's length-masking REVERTED (runtime guards in the 2cy/op inner loop
// cost more than the skipped work: abtt 78->89). Back to R11 bodies, plus
// launch-schedule fusion: (a) three cost kernels -> one 656-block launch;
// (b) sinkhorn_aa folded into the abtt launch (1508 blocks, aa re-shaped for
// 256 threads, no x-cache so VGPR ~90 doesn't throttle ab occupancy).
// Dispatches 7 -> 4; tt/aa work hides under the dominant ab blocks.
// Base: exact 2-pass cached-x LSE (R11), MFMA split-bf16 costs (R7), native
// v_exp/v_log (R9). Launch-bounds law: never pass arg2 (R3/R4).

namespace {
constexpr int NB = 128, NL = 128, ND = 300, NK = 10, NR = 50, NITER = 20;
constexpr float LOG2E   = 1.4426950408889634f;
constexpr float EPS     = 0.0025f;                  // blur^p = 0.05^2
constexpr float CSCALE  = 0.5f * LOG2E / EPS;       // squared-dist -> log2-domain cost
constexpr float VSCALE  = EPS * 0.6931471805599453f; // log2-potential -> nat (eps*ln2)
constexpr float LOG2_50 = 5.6438561897747395f;      // log2(50)
constexpr float NEGL2   = -1.442695e9f;             // -1e9 * log2e
constexpr float SENT    = -3.0e38f;                 // sentinel (exp2 -> 0)
constexpr int KCH = 10;                              // K chunks of 32
constexpr int PIT = 40;                              // LDS pitch in shorts
// merged-grid layout
constexpr int NAB_TILES = 512;                       // ab cost tiles (128 x 4)
constexpr int NTT_TILES = 16;                        // tt cost tiles (4 x 4)
constexpr int SK_AB = NB * NK;                       // 1280
constexpr int SK_TT = NK * NK;                       // 100
}

typedef __attribute__((ext_vector_type(8))) short bf16x8;
typedef __attribute__((ext_vector_type(4))) float f32x4;

__device__ inline float ex2(float x) { return __builtin_amdgcn_exp2f(x); }
__device__ inline float lg2(float x) { return __builtin_amdgcn_logf(x); }
__device__ inline f32x4 vmax4(f32x4 a, f32x4 b) {
  f32x4 r;
  r[0] = fmaxf(a[0], b[0]); r[1] = fmaxf(a[1], b[1]);
  r[2] = fmaxf(a[2], b[2]); r[3] = fmaxf(a[3], b[3]);
  return r;
}
__device__ inline f32x4 vexp4(f32x4 x) {
  f32x4 r;
  r[0] = ex2(x[0]); r[1] = ex2(x[1]); r[2] = ex2(x[2]); r[3] = ex2(x[3]);
  return r;
}

__device__ inline unsigned short f2bf_rn(float x) {
  unsigned int u = __float_as_uint(x);
  unsigned int r = (u + 0x7fffu + ((u >> 16) & 1u)) >> 16;
  return (unsigned short)r;
}
__device__ inline float bf2f(unsigned short h) {
  return __uint_as_float((unsigned int)h << 16);
}

// ---------------------------------------------------------------- prep
__global__ void prep_kernel(const float* __restrict__ anchor,
                            const float* __restrict__ weight,
                            const float* __restrict__ t0,
                            const int* __restrict__ len,
                            float* __restrict__ na, float* __restrict__ nt,
                            float* __restrict__ lw2) {
  int wid  = (blockIdx.x * blockDim.x + threadIdx.x) >> 6;
  int lane = threadIdx.x & 63;
  const int nA = NB * NL;
  const int total = nA + NK * NR;
  if (wid >= total) return;
  const float* src = (wid < nA) ? (anchor + (size_t)wid * ND)
                                : (t0 + (size_t)(wid - nA) * ND);
  float s = 0.f;
  for (int d = lane; d < ND; d += 64) { float v = src[d]; s += v * v; }
  #pragma unroll
  for (int off = 32; off; off >>= 1) s += __shfl_xor(s, off);
  if (lane == 0) { if (wid < nA) na[wid] = s; else nt[wid - nA] = s; }
  if (wid < nA && lane == 1) {
    int b = wid >> 7, l = wid & 127;
    float w = weight[wid];
    lw2[wid] = (l < len[b]) ? log2f(fmaxf(w, 1e-12f)) : NEGL2;
  }
}

// ---------------------------------------------------------------- staging helper
__device__ inline void stage8(const float* __restrict__ src, bool rowvalid,
                              int kg, short* __restrict__ Hs, short* __restrict__ Ls,
                              int lofs) {
  float xv[8];
  if (rowvalid && kg + 8 <= ND) {
    float4 u = *(const float4*)(src + kg);
    float4 v = *(const float4*)(src + kg + 4);
    xv[0]=u.x; xv[1]=u.y; xv[2]=u.z; xv[3]=u.w;
    xv[4]=v.x; xv[5]=v.y; xv[6]=v.z; xv[7]=v.w;
  } else {
    #pragma unroll
    for (int e = 0; e < 8; ++e)
      xv[e] = (rowvalid && kg + e < ND) ? src[kg + e] : 0.f;
  }
  bf16x8 hv, lv;
  #pragma unroll
  for (int e = 0; e < 8; ++e) {
    unsigned short h = f2bf_rn(xv[e]);
    float hf = bf2f(h);
    unsigned short l = f2bf_rn(xv[e] - hf);
    hv[e] = (short)h; lv[e] = (short)l;
  }
  *(bf16x8*)(Hs + lofs) = hv;
  *(bf16x8*)(Ls + lofs) = lv;
}

// ---------------------------------------------------------------- cost (all three, one launch)
// blk [0,512): ab tiles (ti=blk&127, tj=blk>>7); [512,528): tt; [528,656): aa.
__global__ __launch_bounds__(512)
void cost_all(const float* __restrict__ anchor, const float* __restrict__ t0,
              const float* __restrict__ na, const float* __restrict__ nt,
              float* __restrict__ Cab, float* __restrict__ Ctt,
              float* __restrict__ Caa) {
  __shared__ __align__(16) short Ah[128 * PIT], Al[128 * PIT];
  __shared__ __align__(16) short Bh[128 * PIT], Bl[128 * PIT];

  const int blk = blockIdx.x;
  const int t = threadIdx.x;
  const int lane = t & 63, w = t >> 6;
  const int fr = lane & 15, fo = (lane >> 4) * 8;
  const int srow = t >> 2, skq = t & 3, kloc = skq * 8;
  const int lofs = srow * PIT + kloc;
  const int aofs = (w * 16 + fr) * PIT + fo;

  f32x4 acc[8];
  #pragma unroll
  for (int cc = 0; cc < 8; ++cc) acc[cc] = (f32x4){0.f, 0.f, 0.f, 0.f};

  if (blk < NAB_TILES + NTT_TILES) {
    // ------------------------------ ab / tt tile
    const float *X, *Y, *NXp, *NYp; float* C;
    int nX, nY, mode, i0, j0;
    if (blk < NAB_TILES) {
      X = anchor; Y = t0; NXp = na; NYp = nt; C = Cab;
      nX = NB * NL; nY = NK * NR; mode = 0;
      i0 = (blk & 127) * 128; j0 = (blk >> 7) * 128;
    } else {
      int q = blk - NAB_TILES;
      X = t0; Y = t0; NXp = nt; NYp = nt; C = Ctt;
      nX = NK * NR; nY = NK * NR; mode = 2;
      i0 = (q >> 2) * 128; j0 = (q & 3) * 128;
    }
    const bool avalid = (i0 + srow) < nX;
    const bool bvalid = (j0 + srow) < nY;
    const float* aro = X + (size_t)(i0 + srow) * ND;
    const float* bro = Y + (size_t)(j0 + srow) * ND;

    for (int c = 0; c < KCH; ++c) {
      int kg = c * 32 + kloc;
      stage8(aro, avalid, kg, Ah, Al, lofs);
      stage8(bro, bvalid, kg, Bh, Bl, lofs);
      __syncthreads();

      bf16x8 ah = *(const bf16x8*)(Ah + aofs);
      bf16x8 al = *(const bf16x8*)(Al + aofs);
      #pragma unroll
      for (int cc = 0; cc < 8; ++cc) {
        int bofs = (cc * 16 + fr) * PIT + fo;
        bf16x8 bh = *(const bf16x8*)(Bh + bofs);
        bf16x8 bl = *(const bf16x8*)(Bl + bofs);
        acc[cc] = __builtin_amdgcn_mfma_f32_16x16x32_bf16(ah, bh, acc[cc], 0, 0, 0);
        acc[cc] = __builtin_amdgcn_mfma_f32_16x16x32_bf16(ah, bl, acc[cc], 0, 0, 0);
        acc[cc] = __builtin_amdgcn_mfma_f32_16x16x32_bf16(al, bh, acc[cc], 0, 0, 0);
      }
      __syncthreads();
    }

    #pragma unroll
    for (int cc = 0; cc < 8; ++cc) {
      int gj = j0 + cc * 16 + fr;
      if (gj >= nY) continue;
      float ny = NYp[gj];
      #pragma unroll
      for (int reg = 0; reg < 4; ++reg) {
        int gi = i0 + w * 16 + (lane >> 4) * 4 + reg;
        if (gi >= nX) continue;
        float sq = NXp[gi] + ny - 2.f * acc[cc][reg];
        float cv = fmaxf(sq, 0.f) * CSCALE;
        if (mode == 0) {
          int k = gj / 50, jj = gj - k * 50;
          C[((size_t)((gi >> 7) * NK + k)) * (NL * NR) + (gi & 127) * NR + jj] = cv;
        } else {
          int ki = gi / 50, ii = gi - ki * 50;
          int kj = gj / 50, jj = gj - kj * 50;
          C[((size_t)(ki * NK + kj)) * (NR * NR) + ii * NR + jj] = cv;
        }
      }
    }
  } else {
    // ------------------------------ aa (A = B = anchor rows of batch b)
    const int b = blk - (NAB_TILES + NTT_TILES);
    const float* aro = anchor + (size_t)(b * NL + srow) * ND;

    for (int c = 0; c < KCH; ++c) {
      stage8(aro, true, c * 32 + kloc, Ah, Al, lofs);
      __syncthreads();

      bf16x8 ah = *(const bf16x8*)(Ah + aofs);
      bf16x8 al = *(const bf16x8*)(Al + aofs);
      #pragma unroll
      for (int cc = 0; cc < 8; ++cc) {
        int bofs = (cc * 16 + fr) * PIT + fo;
        bf16x8 bh = *(const bf16x8*)(Ah + bofs);
        bf16x8 bl = *(const bf16x8*)(Al + bofs);
        acc[cc] = __builtin_amdgcn_mfma_f32_16x16x32_bf16(ah, bh, acc[cc], 0, 0, 0);
        acc[cc] = __builtin_amdgcn_mfma_f32_16x16x32_bf16(ah, bl, acc[cc], 0, 0, 0);
        acc[cc] = __builtin_amdgcn_mfma_f32_16x16x32_bf16(al, bh, acc[cc], 0, 0, 0);
      }
      __syncthreads();
    }

    const float* nb = na + b * NL;
    float* Cb = Caa + (size_t)b * (NL * NL);
    #pragma unroll
    for (int cc = 0; cc < 8; ++cc) {
      int gj = cc * 16 + fr;
      float ny = nb[gj];
      #pragma unroll
      for (int reg = 0; reg < 4; ++reg) {
        int gi = w * 16 + (lane >> 4) * 4 + reg;
        float sq = nb[gi] + ny - 2.f * acc[cc][reg];
        Cb[(size_t)gi * NL + gj] = fmaxf(sq, 0.f) * CSCALE;
      }
    }
  }
}

// ---------------------------------------------------------------- sinkhorn (all three, one launch)
// blk [0,1280): ab; [1280,1380): tt; [1380,1508): aa (256-thread reshape).
__global__ __launch_bounds__(256)
void sinkhorn_all(const float* __restrict__ Cab, const float* __restrict__ Ctt,
                  const float* __restrict__ Caa,
                  const float* __restrict__ lw2, const float* __restrict__ weight,
                  float* __restrict__ oab, float* __restrict__ ott,
                  float* __restrict__ oaa) {
  __shared__ __align__(16) float smem[444];
  const int t = threadIdx.x;

  if (blockIdx.x < SK_AB) {
    // ------------------------------ ab body (128x50) -- R11 verbatim
    float* g2    = smem;                 // 56 (50 real + 6 SENT pads)
    float* f2    = smem + 56;            // 128
    float* potf2 = smem + 184;           // 128 (16B-aligned)
    float* la2s  = smem + 312;           // 128
    float* red   = smem + 440;           // 4
    int p = blockIdx.x, b = p / NK;
    const float* Cp = Cab + (size_t)p * (NL * NR);
    if (t < NL) la2s[t] = lw2[b * NL + t];
    if (t < NR) g2[t] = 0.f;
    else if (t < 56) g2[t] = SENT;

    const int rf = t >> 1, sf = t & 1;
    f32x4 Crow4[7];
    {
      const float* rp = Cp + rf * NR;
      #pragma unroll
      for (int q = 0; q < 7; ++q)
        #pragma unroll
        for (int e = 0; e < 4; ++e) {
          int col = sf * 28 + q * 4 + e;
          Crow4[q][e] = (col < NR) ? -rp[col] : 0.f;
        }
    }
    const int cc = t >> 2, sc = t & 3;
    f32x4 Ccol4[8];
    if (t < 200) {
      #pragma unroll
      for (int q = 0; q < 8; ++q)
        #pragma unroll
        for (int e = 0; e < 4; ++e)
          Ccol4[q][e] = -Cp[(sc * 32 + q * 4 + e) * NR + cc];
    }
    __syncthreads();

    const f32x4* g4base = (const f32x4*)(g2 + sf * 28);
    const f32x4* f4base = (const f32x4*)(potf2 + sc * 32);

    for (int it = 0; it < NITER; ++it) {
      {
        f32x4 x[7];
        f32x4 m4 = {SENT, SENT, SENT, SENT};
        #pragma unroll
        for (int q = 0; q < 7; ++q) {
          x[q] = g4base[q] + Crow4[q];
          m4 = vmax4(m4, x[q]);
        }
        float mx = fmaxf(fmaxf(m4[0], m4[1]), fmaxf(m4[2], m4[3]));
        mx = fmaxf(mx, __shfl_xor(mx, 1));
        f32x4 s4 = {0.f, 0.f, 0.f, 0.f};
        #pragma unroll
        for (int q = 0; q < 7; ++q) s4 += vexp4(x[q] - mx);
        float s = (s4[0] + s4[1]) + (s4[2] + s4[3]);
        s += __shfl_xor(s, 1);
        if (sf == 0) {
          float fv = LOG2_50 - mx - lg2(s);
          f2[rf] = fv; potf2[rf] = la2s[rf] + fv;
        }
      }
      __syncthreads();
      if (t < 200) {
        f32x4 x[8];
        f32x4 m4 = {SENT, SENT, SENT, SENT};
        #pragma unroll
        for (int q = 0; q < 8; ++q) {
          x[q] = f4base[q] + Ccol4[q];
          m4 = vmax4(m4, x[q]);
        }
        float mx = fmaxf(fmaxf(m4[0], m4[1]), fmaxf(m4[2], m4[3]));
        mx = fmaxf(mx, __shfl_xor(mx, 1));
        mx = fmaxf(mx, __shfl_xor(mx, 2));
        f32x4 s4 = {0.f, 0.f, 0.f, 0.f};
        #pragma unroll
        for (int q = 0; q < 8; ++q) s4 += vexp4(x[q] - mx);
        float s = (s4[0] + s4[1]) + (s4[2] + s4[3]);
        s += __shfl_xor(s, 1);
        s += __shfl_xor(s, 2);
        if (sc == 0) g2[cc] = -(mx + lg2(s));
      }
      __syncthreads();
    }

    float acc = 0.f;
    if (t < NL) acc = weight[b * NL + t] * f2[t];
    else if (t < NL + NR) acc = g2[t - NL] * (1.0f / NR);
    #pragma unroll
    for (int off = 32; off; off >>= 1) acc += __shfl_xor(acc, off);
    if ((t & 63) == 0) red[t >> 6] = acc;
    __syncthreads();
    if (t == 0) oab[p] = VSCALE * (red[0] + red[1] + red[2] + red[3]);

  } else if (blockIdx.x < SK_AB + SK_TT) {
    // ------------------------------ tt body (50x50) -- R11 verbatim
    float* f2 = smem;                    // 50
    float* g2 = smem + 56;               // 50
    float* red = smem + 112;             // 4
    int p = blockIdx.x - SK_AB;
    const float* Cp = Ctt + (size_t)p * (NR * NR);
    if (t < NR) g2[t] = 0.f;

    const int r = t >> 2, sub = t & 3;
    const bool act = (t < 200);
    float Crowb[13], Ccolb[13];
    if (act) {
      #pragma unroll
      for (int j = 0; j < 13; ++j) {
        int idx = sub + 4 * j;
        Crowb[j] = (idx < NR) ? -Cp[r * NR + idx] : SENT;
        Ccolb[j] = (idx < NR) ? -Cp[idx * NR + r] : SENT;
      }
    }
    __syncthreads();

    for (int it = 0; it < NITER; ++it) {
      if (act) {
        float x[13];
        float m0 = SENT, m1 = SENT;
        #pragma unroll
        for (int j = 0; j < 12; j += 2) {
          x[j]     = g2[sub + 4 * j]       + Crowb[j];
          x[j + 1] = g2[sub + 4 * (j + 1)] + Crowb[j + 1];
          m0 = fmaxf(m0, x[j]); m1 = fmaxf(m1, x[j + 1]);
        }
        { int i0 = sub + 48; x[12] = ((i0 < NR) ? g2[i0] : 0.f) + Crowb[12];
          m0 = fmaxf(m0, x[12]); }
        float mx = fmaxf(m0, m1);
        mx = fmaxf(mx, __shfl_xor(mx, 1));
        mx = fmaxf(mx, __shfl_xor(mx, 2));
        float s0 = 0.f, s1 = 0.f;
        #pragma unroll
        for (int j = 0; j < 12; j += 2) {
          s0 += ex2(x[j] - mx); s1 += ex2(x[j + 1] - mx);
        }
        s0 += ex2(x[12] - mx);
        float s = s0 + s1;
        s += __shfl_xor(s, 1);
        s += __shfl_xor(s, 2);
        if (sub == 0) f2[r] = LOG2_50 - mx - lg2(s);
      }
      __syncthreads();
      if (act) {
        float x[13];
        float m0 = SENT, m1 = SENT;
        #pragma unroll
        for (int j = 0; j < 12; j += 2) {
          x[j]     = f2[sub + 4 * j]       + Ccolb[j];
          x[j + 1] = f2[sub + 4 * (j + 1)] + Ccolb[j + 1];
          m0 = fmaxf(m0, x[j]); m1 = fmaxf(m1, x[j + 1]);
        }
        { int i0 = sub + 48; x[12] = ((i0 < NR) ? f2[i0] : 0.f) + Ccolb[12];
          m0 = fmaxf(m0, x[12]); }
        float mx = fmaxf(m0, m1);
        mx = fmaxf(mx, __shfl_xor(mx, 1));
        mx = fmaxf(mx, __shfl_xor(mx, 2));
        float s0 = 0.f, s1 = 0.f;
        #pragma unroll
        for (int j = 0; j < 12; j += 2) {
          s0 += ex2(x[j] - mx); s1 += ex2(x[j + 1] - mx);
        }
        s0 += ex2(x[12] - mx);
        float s = s0 + s1;
        s += __shfl_xor(s, 1);
        s += __shfl_xor(s, 2);
        if (sub == 0) g2[r] = LOG2_50 - mx - lg2(s);
      }
      __syncthreads();
    }

    float acc = 0.f;
    if (t < NR) acc = f2[t] + g2[t];
    #pragma unroll
    for (int off = 32; off; off >>= 1) acc += __shfl_xor(acc, off);
    if ((t & 63) == 0) red[t >> 6] = acc;
    __syncthreads();
    if (t == 0) ott[p] = VSCALE * (1.0f / NR) * (red[0] + red[1] + red[2] + red[3]);

  } else {
    // ------------------------------ aa body, 256-thread reshape
    // 2 threads/row (r=t>>1, sub=t&1), 16 quads: cols 8q+4sub..+3.
    // No x-cache (keeps VGPR ~90 so ab blocks' occupancy isn't throttled);
    // pass 2 re-reads potentials from LDS (broadcast, conflict-free).
    float* pF  = smem;                   // 128
    float* pG  = smem + 128;             // 128
    float* red = smem + 256;             // 4
    int b = blockIdx.x - (SK_AB + SK_TT);
    const int r = t >> 1, sub = t & 1;
    const float* Cr = Caa + (size_t)b * (NL * NL) + (size_t)r * NL;
    const float* lp = lw2 + b * NL;
    f32x4 Cr4[16];                       // la2[col] - C[r][col]
    #pragma unroll
    for (int q = 0; q < 16; ++q) {
      int c0 = q * 8 + sub * 4;
      float4 cv = *(const float4*)(Cr + c0);
      float4 lv = *(const float4*)(lp + c0);
      Cr4[q] = (f32x4){lv.x - cv.x, lv.y - cv.y, lv.z - cv.z, lv.w - cv.w};
    }
    if (t < NL) { pG[t] = 0.f; pF[t] = 0.f; }
    __syncthreads();

    for (int it = 0; it < NITER; ++it) {
      // ---- f = T(g)
      {
        f32x4 m4 = {SENT, SENT, SENT, SENT};
        #pragma unroll
        for (int q = 0; q < 16; ++q)
          m4 = vmax4(m4, *(const f32x4*)(pG + q * 8 + sub * 4) + Cr4[q]);
        float mx = fmaxf(fmaxf(m4[0], m4[1]), fmaxf(m4[2], m4[3]));
        mx = fmaxf(mx, __shfl_xor(mx, 1));
        f32x4 s4 = {0.f, 0.f, 0.f, 0.f};
        #pragma unroll
        for (int q = 0; q < 16; ++q)
          s4 += vexp4(*(const f32x4*)(pG + q * 8 + sub * 4) + Cr4[q] - mx);
        float s = (s4[0] + s4[1]) + (s4[2] + s4[3]);
        s += __shfl_xor(s, 1);
        if (sub == 0) pF[r] = -(mx + lg2(s));
      }
      __syncthreads();
      // ---- g = T(f)
      {
        f32x4 m4 = {SENT, SENT, SENT, SENT};
        #pragma unroll
        for (int q = 0; q < 16; ++q)
          m4 = vmax4(m4, *(const f32x4*)(pF + q * 8 + sub * 4) + Cr4[q]);
        float mx = fmaxf(fmaxf(m4[0], m4[1]), fmaxf(m4[2], m4[3]));
        mx = fmaxf(mx, __shfl_xor(mx, 1));
        f32x4 s4 = {0.f, 0.f, 0.f, 0.f};
        #pragma unroll
        for (int q = 0; q < 16; ++q)
          s4 += vexp4(*(const f32x4*)(pF + q * 8 + sub * 4) + Cr4[q] - mx);
        float s = (s4[0] + s4[1]) + (s4[2] + s4[3]);
        s += __shfl_xor(s, 1);
        if (sub == 0) pG[r] = -(mx + lg2(s));
      }
      __syncthreads();
    }

    float acc = 0.f;
    if (t < NL) acc = weight[b * NL + t] * (pF[t] + pG[t]);
    #pragma unroll
    for (int off = 32; off; off >>= 1) acc += __shfl_xor(acc, off);
    if ((t & 63) == 0) red[t >> 6] = acc;
    __syncthreads();
    if (t == 0) oaa[b] = VSCALE * (red[0] + red[1] + red[2] + red[3]);
  }
}

// ---------------------------------------------------------------- finalize
__global__ void finalize_kernel(const float* __restrict__ oab, const float* __restrict__ oaa,
                                const float* __restrict__ ott, const int* __restrict__ grade,
                                float* __restrict__ out) {
  __shared__ float selft[NK];
  __shared__ float redL[4], redD[4];
  int t = threadIdx.x;
  if (t < NK) selft[t] = ott[t * NK + t];
  __syncthreads();
  float dpart = (t < NK * NK) ? ott[t] : 0.f;
  float lpart = 0.f;
  if (t < NB) {
    int g = grade[t];
    float oa = oaa[t];
    float dpos = oab[t * NK + g] - 0.5f * (oa + selft[g]);
    float s = 0.f;
    #pragma unroll
    for (int k = 0; k < NK; ++k) {
      float dk = oab[t * NK + k] - 0.5f * (oa + selft[k]);
      s += fmaxf(dpos - dk + 10.0f, 0.0f);
    }
    lpart = s - 10.0f;
  }
  #pragma unroll
  for (int off = 32; off; off >>= 1) {
    dpart += __shfl_xor(dpart, off);
    lpart += __shfl_xor(lpart, off);
  }
  if ((t & 63) == 0) { redD[t >> 6] = dpart; redL[t >> 6] = lpart; }
  __syncthreads();
  if (t == 0) {
    float ds = 0.f, ls = 0.f;
    #pragma unroll
    for (int i = 0; i < 4; ++i) { ds += redD[i]; ls += redL[i]; }
    float ss = 0.f;
    #pragma unroll
    for (int k = 0; k < NK; ++k) ss += selft[k];
    float dis = ds - (float)NK * ss;
    out[0] = ls / (float)NB - dis * 0.01f;
  }
}

// ---------------------------------------------------------------- launch
extern "C" void kernel_launch(void* const* d_in, const int* in_sizes, int n_in,
                              void* d_out, int out_size, void* d_ws, size_t ws_size,
                              hipStream_t stream) {
  (void)in_sizes; (void)n_in; (void)out_size; (void)ws_size;
  const float* anchor = (const float*)d_in[0];
  const float* weight = (const float*)d_in[1];
  const float* t0     = (const float*)d_in[2];
  const int*   len    = (const int*)d_in[3];
  const int*   grade  = (const int*)d_in[4];
  float* out = (float*)d_out;

  float* ws  = (float*)d_ws;
  float* Cab = ws;                                    // 819200
  float* Caa = Cab + (size_t)NB * NK * NL * NR;       // 2097152
  float* Ctt = Caa + (size_t)NB * NL * NL;            // 250000
  float* na  = Ctt + (size_t)NK * NK * NR * NR;       // 16384
  float* nt  = na + NB * NL;                          // 500
  float* lw2 = nt + NK * NR;                          // 16384
  float* oab = lw2 + NB * NL;                         // 1280
  float* oaa = oab + NB * NK;                         // 128
  float* ott = oaa + NB;                              // 100

  prep_kernel<<<(NB * NL + NK * NR) / 4, 256, 0, stream>>>(anchor, weight, t0, len, na, nt, lw2);
  cost_all<<<NAB_TILES + NTT_TILES + NB, 512, 0, stream>>>(anchor, t0, na, nt,
                                                           Cab, Ctt, Caa);
  sinkhorn_all<<<SK_AB + SK_TT + NB, 256, 0, stream>>>(Cab, Ctt, Caa, lw2, weight,
                                                       oab, ott, oaa);
  finalize_kernel<<<1, 256, 0, stream>>>(oab, oaa, ott, grade, out);
}

// Round 18
// 164.625 us; speedup vs baseline: 1.3558x; 1.0042x over previous
//
#include <hip/hip_runtime.h>
#include <math.h>

// Sinkhorn-divergence triplet loss (geomloss-style), MI355X.
// R13: R12's length-masking REVERTED (runtime guards in the 2cy/op inner loop
// cost more than the skipped work: abtt 78->89). Back to R11 bodies, plus
// launch-schedule fusion: (a) three cost kernels -> one 656-block launch;
// (b) sinkhorn_aa folded into the abtt launch (1508 blocks, aa re-shaped for
// 256 threads, no x-cache so VGPR ~90 doesn't throttle ab occupancy).
// Dispatches 7 -> 4; tt/aa work hides under the dominant ab blocks.
// Base: exact 2-pass cached-x LSE (R11), MFMA split-bf16 costs (R7), native
// v_exp/v_log (R9). Launch-bounds law: never pass arg2 (R3/R4).
// R18 NOTE: this is the R13 source byte-for-byte. R14-R17 all grew the
// workspace layout past R13's 12,804,512-byte footprint (by 48B..21MB) and
// ALL failed with garbage absmax; the <=R13 layout has never failed. ws_size
// is evidently within ~48B of that footprint: NEVER extend this layout.

namespace {
constexpr int NB = 128, NL = 128, ND = 300, NK = 10, NR = 50, NITER = 20;
constexpr float LOG2E   = 1.4426950408889634f;
constexpr float EPS     = 0.0025f;                  // blur^p = 0.05^2
constexpr float CSCALE  = 0.5f * LOG2E / EPS;       // squared-dist -> log2-domain cost
constexpr float VSCALE  = EPS * 0.6931471805599453f; // log2-potential -> nat (eps*ln2)
constexpr float LOG2_50 = 5.6438561897747395f;      // log2(50)
constexpr float NEGL2   = -1.442695e9f;             // -1e9 * log2e
constexpr float SENT    = -3.0e38f;                 // sentinel (exp2 -> 0)
constexpr int KCH = 10;                              // K chunks of 32
constexpr int PIT = 40;                              // LDS pitch in shorts
// merged-grid layout
constexpr int NAB_TILES = 512;                       // ab cost tiles (128 x 4)
constexpr int NTT_TILES = 16;                        // tt cost tiles (4 x 4)
constexpr int SK_AB = NB * NK;                       // 1280
constexpr int SK_TT = NK * NK;                       // 100
}

typedef __attribute__((ext_vector_type(8))) short bf16x8;
typedef __attribute__((ext_vector_type(4))) float f32x4;

__device__ inline float ex2(float x) { return __builtin_amdgcn_exp2f(x); }
__device__ inline float lg2(float x) { return __builtin_amdgcn_logf(x); }
__device__ inline f32x4 vmax4(f32x4 a, f32x4 b) {
  f32x4 r;
  r[0] = fmaxf(a[0], b[0]); r[1] = fmaxf(a[1], b[1]);
  r[2] = fmaxf(a[2], b[2]); r[3] = fmaxf(a[3], b[3]);
  return r;
}
__device__ inline f32x4 vexp4(f32x4 x) {
  f32x4 r;
  r[0] = ex2(x[0]); r[1] = ex2(x[1]); r[2] = ex2(x[2]); r[3] = ex2(x[3]);
  return r;
}

__device__ inline unsigned short f2bf_rn(float x) {
  unsigned int u = __float_as_uint(x);
  unsigned int r = (u + 0x7fffu + ((u >> 16) & 1u)) >> 16;
  return (unsigned short)r;
}
__device__ inline float bf2f(unsigned short h) {
  return __uint_as_float((unsigned int)h << 16);
}

// ---------------------------------------------------------------- prep
__global__ void prep_kernel(const float* __restrict__ anchor,
                            const float* __restrict__ weight,
                            const float* __restrict__ t0,
                            const int* __restrict__ len,
                            float* __restrict__ na, float* __restrict__ nt,
                            float* __restrict__ lw2) {
  int wid  = (blockIdx.x * blockDim.x + threadIdx.x) >> 6;
  int lane = threadIdx.x & 63;
  const int nA = NB * NL;
  const int total = nA + NK * NR;
  if (wid >= total) return;
  const float* src = (wid < nA) ? (anchor + (size_t)wid * ND)
                                : (t0 + (size_t)(wid - nA) * ND);
  float s = 0.f;
  for (int d = lane; d < ND; d += 64) { float v = src[d]; s += v * v; }
  #pragma unroll
  for (int off = 32; off; off >>= 1) s += __shfl_xor(s, off);
  if (lane == 0) { if (wid < nA) na[wid] = s; else nt[wid - nA] = s; }
  if (wid < nA && lane == 1) {
    int b = wid >> 7, l = wid & 127;
    float w = weight[wid];
    lw2[wid] = (l < len[b]) ? log2f(fmaxf(w, 1e-12f)) : NEGL2;
  }
}

// ---------------------------------------------------------------- staging helper
__device__ inline void stage8(const float* __restrict__ src, bool rowvalid,
                              int kg, short* __restrict__ Hs, short* __restrict__ Ls,
                              int lofs) {
  float xv[8];
  if (rowvalid && kg + 8 <= ND) {
    float4 u = *(const float4*)(src + kg);
    float4 v = *(const float4*)(src + kg + 4);
    xv[0]=u.x; xv[1]=u.y; xv[2]=u.z; xv[3]=u.w;
    xv[4]=v.x; xv[5]=v.y; xv[6]=v.z; xv[7]=v.w;
  } else {
    #pragma unroll
    for (int e = 0; e < 8; ++e)
      xv[e] = (rowvalid && kg + e < ND) ? src[kg + e] : 0.f;
  }
  bf16x8 hv, lv;
  #pragma unroll
  for (int e = 0; e < 8; ++e) {
    unsigned short h = f2bf_rn(xv[e]);
    float hf = bf2f(h);
    unsigned short l = f2bf_rn(xv[e] - hf);
    hv[e] = (short)h; lv[e] = (short)l;
  }
  *(bf16x8*)(Hs + lofs) = hv;
  *(bf16x8*)(Ls + lofs) = lv;
}

// ---------------------------------------------------------------- cost (all three, one launch)
// blk [0,512): ab tiles (ti=blk&127, tj=blk>>7); [512,528): tt; [528,656): aa.
__global__ __launch_bounds__(512)
void cost_all(const float* __restrict__ anchor, const float* __restrict__ t0,
              const float* __restrict__ na, const float* __restrict__ nt,
              float* __restrict__ Cab, float* __restrict__ Ctt,
              float* __restrict__ Caa) {
  __shared__ __align__(16) short Ah[128 * PIT], Al[128 * PIT];
  __shared__ __align__(16) short Bh[128 * PIT], Bl[128 * PIT];

  const int blk = blockIdx.x;
  const int t = threadIdx.x;
  const int lane = t & 63, w = t >> 6;
  const int fr = lane & 15, fo = (lane >> 4) * 8;
  const int srow = t >> 2, skq = t & 3, kloc = skq * 8;
  const int lofs = srow * PIT + kloc;
  const int aofs = (w * 16 + fr) * PIT + fo;

  f32x4 acc[8];
  #pragma unroll
  for (int cc = 0; cc < 8; ++cc) acc[cc] = (f32x4){0.f, 0.f, 0.f, 0.f};

  if (blk < NAB_TILES + NTT_TILES) {
    // ------------------------------ ab / tt tile
    const float *X, *Y, *NXp, *NYp; float* C;
    int nX, nY, mode, i0, j0;
    if (blk < NAB_TILES) {
      X = anchor; Y = t0; NXp = na; NYp = nt; C = Cab;
      nX = NB * NL; nY = NK * NR; mode = 0;
      i0 = (blk & 127) * 128; j0 = (blk >> 7) * 128;
    } else {
      int q = blk - NAB_TILES;
      X = t0; Y = t0; NXp = nt; NYp = nt; C = Ctt;
      nX = NK * NR; nY = NK * NR; mode = 2;
      i0 = (q >> 2) * 128; j0 = (q & 3) * 128;
    }
    const bool avalid = (i0 + srow) < nX;
    const bool bvalid = (j0 + srow) < nY;
    const float* aro = X + (size_t)(i0 + srow) * ND;
    const float* bro = Y + (size_t)(j0 + srow) * ND;

    for (int c = 0; c < KCH; ++c) {
      int kg = c * 32 + kloc;
      stage8(aro, avalid, kg, Ah, Al, lofs);
      stage8(bro, bvalid, kg, Bh, Bl, lofs);
      __syncthreads();

      bf16x8 ah = *(const bf16x8*)(Ah + aofs);
      bf16x8 al = *(const bf16x8*)(Al + aofs);
      #pragma unroll
      for (int cc = 0; cc < 8; ++cc) {
        int bofs = (cc * 16 + fr) * PIT + fo;
        bf16x8 bh = *(const bf16x8*)(Bh + bofs);
        bf16x8 bl = *(const bf16x8*)(Bl + bofs);
        acc[cc] = __builtin_amdgcn_mfma_f32_16x16x32_bf16(ah, bh, acc[cc], 0, 0, 0);
        acc[cc] = __builtin_amdgcn_mfma_f32_16x16x32_bf16(ah, bl, acc[cc], 0, 0, 0);
        acc[cc] = __builtin_amdgcn_mfma_f32_16x16x32_bf16(al, bh, acc[cc], 0, 0, 0);
      }
      __syncthreads();
    }

    #pragma unroll
    for (int cc = 0; cc < 8; ++cc) {
      int gj = j0 + cc * 16 + fr;
      if (gj >= nY) continue;
      float ny = NYp[gj];
      #pragma unroll
      for (int reg = 0; reg < 4; ++reg) {
        int gi = i0 + w * 16 + (lane >> 4) * 4 + reg;
        if (gi >= nX) continue;
        float sq = NXp[gi] + ny - 2.f * acc[cc][reg];
        float cv = fmaxf(sq, 0.f) * CSCALE;
        if (mode == 0) {
          int k = gj / 50, jj = gj - k * 50;
          C[((size_t)((gi >> 7) * NK + k)) * (NL * NR) + (gi & 127) * NR + jj] = cv;
        } else {
          int ki = gi / 50, ii = gi - ki * 50;
          int kj = gj / 50, jj = gj - kj * 50;
          C[((size_t)(ki * NK + kj)) * (NR * NR) + ii * NR + jj] = cv;
        }
      }
    }
  } else {
    // ------------------------------ aa (A = B = anchor rows of batch b)
    const int b = blk - (NAB_TILES + NTT_TILES);
    const float* aro = anchor + (size_t)(b * NL + srow) * ND;

    for (int c = 0; c < KCH; ++c) {
      stage8(aro, true, c * 32 + kloc, Ah, Al, lofs);
      __syncthreads();

      bf16x8 ah = *(const bf16x8*)(Ah + aofs);
      bf16x8 al = *(const bf16x8*)(Al + aofs);
      #pragma unroll
      for (int cc = 0; cc < 8; ++cc) {
        int bofs = (cc * 16 + fr) * PIT + fo;
        bf16x8 bh = *(const bf16x8*)(Ah + bofs);
        bf16x8 bl = *(const bf16x8*)(Al + bofs);
        acc[cc] = __builtin_amdgcn_mfma_f32_16x16x32_bf16(ah, bh, acc[cc], 0, 0, 0);
        acc[cc] = __builtin_amdgcn_mfma_f32_16x16x32_bf16(ah, bl, acc[cc], 0, 0, 0);
        acc[cc] = __builtin_amdgcn_mfma_f32_16x16x32_bf16(al, bh, acc[cc], 0, 0, 0);
      }
      __syncthreads();
    }

    const float* nb = na + b * NL;
    float* Cb = Caa + (size_t)b * (NL * NL);
    #pragma unroll
    for (int cc = 0; cc < 8; ++cc) {
      int gj = cc * 16 + fr;
      float ny = nb[gj];
      #pragma unroll
      for (int reg = 0; reg < 4; ++reg) {
        int gi = w * 16 + (lane >> 4) * 4 + reg;
        float sq = nb[gi] + ny - 2.f * acc[cc][reg];
        Cb[(size_t)gi * NL + gj] = fmaxf(sq, 0.f) * CSCALE;
      }
    }
  }
}

// ---------------------------------------------------------------- sinkhorn (all three, one launch)
// blk [0,1280): ab; [1280,1380): tt; [1380,1508): aa (256-thread reshape).
__global__ __launch_bounds__(256)
void sinkhorn_all(const float* __restrict__ Cab, const float* __restrict__ Ctt,
                  const float* __restrict__ Caa,
                  const float* __restrict__ lw2, const float* __restrict__ weight,
                  float* __restrict__ oab, float* __restrict__ ott,
                  float* __restrict__ oaa) {
  __shared__ __align__(16) float smem[444];
  const int t = threadIdx.x;

  if (blockIdx.x < SK_AB) {
    // ------------------------------ ab body (128x50) -- R11 verbatim
    float* g2    = smem;                 // 56 (50 real + 6 SENT pads)
    float* f2    = smem + 56;            // 128
    float* potf2 = smem + 184;           // 128 (16B-aligned)
    float* la2s  = smem + 312;           // 128
    float* red   = smem + 440;           // 4
    int p = blockIdx.x, b = p / NK;
    const float* Cp = Cab + (size_t)p * (NL * NR);
    if (t < NL) la2s[t] = lw2[b * NL + t];
    if (t < NR) g2[t] = 0.f;
    else if (t < 56) g2[t] = SENT;

    const int rf = t >> 1, sf = t & 1;
    f32x4 Crow4[7];
    {
      const float* rp = Cp + rf * NR;
      #pragma unroll
      for (int q = 0; q < 7; ++q)
        #pragma unroll
        for (int e = 0; e < 4; ++e) {
          int col = sf * 28 + q * 4 + e;
          Crow4[q][e] = (col < NR) ? -rp[col] : 0.f;
        }
    }
    const int cc = t >> 2, sc = t & 3;
    f32x4 Ccol4[8];
    if (t < 200) {
      #pragma unroll
      for (int q = 0; q < 8; ++q)
        #pragma unroll
        for (int e = 0; e < 4; ++e)
          Ccol4[q][e] = -Cp[(sc * 32 + q * 4 + e) * NR + cc];
    }
    __syncthreads();

    const f32x4* g4base = (const f32x4*)(g2 + sf * 28);
    const f32x4* f4base = (const f32x4*)(potf2 + sc * 32);

    for (int it = 0; it < NITER; ++it) {
      {
        f32x4 x[7];
        f32x4 m4 = {SENT, SENT, SENT, SENT};
        #pragma unroll
        for (int q = 0; q < 7; ++q) {
          x[q] = g4base[q] + Crow4[q];
          m4 = vmax4(m4, x[q]);
        }
        float mx = fmaxf(fmaxf(m4[0], m4[1]), fmaxf(m4[2], m4[3]));
        mx = fmaxf(mx, __shfl_xor(mx, 1));
        f32x4 s4 = {0.f, 0.f, 0.f, 0.f};
        #pragma unroll
        for (int q = 0; q < 7; ++q) s4 += vexp4(x[q] - mx);
        float s = (s4[0] + s4[1]) + (s4[2] + s4[3]);
        s += __shfl_xor(s, 1);
        if (sf == 0) {
          float fv = LOG2_50 - mx - lg2(s);
          f2[rf] = fv; potf2[rf] = la2s[rf] + fv;
        }
      }
      __syncthreads();
      if (t < 200) {
        f32x4 x[8];
        f32x4 m4 = {SENT, SENT, SENT, SENT};
        #pragma unroll
        for (int q = 0; q < 8; ++q) {
          x[q] = f4base[q] + Ccol4[q];
          m4 = vmax4(m4, x[q]);
        }
        float mx = fmaxf(fmaxf(m4[0], m4[1]), fmaxf(m4[2], m4[3]));
        mx = fmaxf(mx, __shfl_xor(mx, 1));
        mx = fmaxf(mx, __shfl_xor(mx, 2));
        f32x4 s4 = {0.f, 0.f, 0.f, 0.f};
        #pragma unroll
        for (int q = 0; q < 8; ++q) s4 += vexp4(x[q] - mx);
        float s = (s4[0] + s4[1]) + (s4[2] + s4[3]);
        s += __shfl_xor(s, 1);
        s += __shfl_xor(s, 2);
        if (sc == 0) g2[cc] = -(mx + lg2(s));
      }
      __syncthreads();
    }

    float acc = 0.f;
    if (t < NL) acc = weight[b * NL + t] * f2[t];
    else if (t < NL + NR) acc = g2[t - NL] * (1.0f / NR);
    #pragma unroll
    for (int off = 32; off; off >>= 1) acc += __shfl_xor(acc, off);
    if ((t & 63) == 0) red[t >> 6] = acc;
    __syncthreads();
    if (t == 0) oab[p] = VSCALE * (red[0] + red[1] + red[2] + red[3]);

  } else if (blockIdx.x < SK_AB + SK_TT) {
    // ------------------------------ tt body (50x50) -- R11 verbatim
    float* f2 = smem;                    // 50
    float* g2 = smem + 56;               // 50
    float* red = smem + 112;             // 4
    int p = blockIdx.x - SK_AB;
    const float* Cp = Ctt + (size_t)p * (NR * NR);
    if (t < NR) g2[t] = 0.f;

    const int r = t >> 2, sub = t & 3;
    const bool act = (t < 200);
    float Crowb[13], Ccolb[13];
    if (act) {
      #pragma unroll
      for (int j = 0; j < 13; ++j) {
        int idx = sub + 4 * j;
        Crowb[j] = (idx < NR) ? -Cp[r * NR + idx] : SENT;
        Ccolb[j] = (idx < NR) ? -Cp[idx * NR + r] : SENT;
      }
    }
    __syncthreads();

    for (int it = 0; it < NITER; ++it) {
      if (act) {
        float x[13];
        float m0 = SENT, m1 = SENT;
        #pragma unroll
        for (int j = 0; j < 12; j += 2) {
          x[j]     = g2[sub + 4 * j]       + Crowb[j];
          x[j + 1] = g2[sub + 4 * (j + 1)] + Crowb[j + 1];
          m0 = fmaxf(m0, x[j]); m1 = fmaxf(m1, x[j + 1]);
        }
        { int i0 = sub + 48; x[12] = ((i0 < NR) ? g2[i0] : 0.f) + Crowb[12];
          m0 = fmaxf(m0, x[12]); }
        float mx = fmaxf(m0, m1);
        mx = fmaxf(mx, __shfl_xor(mx, 1));
        mx = fmaxf(mx, __shfl_xor(mx, 2));
        float s0 = 0.f, s1 = 0.f;
        #pragma unroll
        for (int j = 0; j < 12; j += 2) {
          s0 += ex2(x[j] - mx); s1 += ex2(x[j + 1] - mx);
        }
        s0 += ex2(x[12] - mx);
        float s = s0 + s1;
        s += __shfl_xor(s, 1);
        s += __shfl_xor(s, 2);
        if (sub == 0) f2[r] = LOG2_50 - mx - lg2(s);
      }
      __syncthreads();
      if (act) {
        float x[13];
        float m0 = SENT, m1 = SENT;
        #pragma unroll
        for (int j = 0; j < 12; j += 2) {
          x[j]     = f2[sub + 4 * j]       + Ccolb[j];
          x[j + 1] = f2[sub + 4 * (j + 1)] + Ccolb[j + 1];
          m0 = fmaxf(m0, x[j]); m1 = fmaxf(m1, x[j + 1]);
        }
        { int i0 = sub + 48; x[12] = ((i0 < NR) ? f2[i0] : 0.f) + Ccolb[12];
          m0 = fmaxf(m0, x[12]); }
        float mx = fmaxf(m0, m1);
        mx = fmaxf(mx, __shfl_xor(mx, 1));
        mx = fmaxf(mx, __shfl_xor(mx, 2));
        float s0 = 0.f, s1 = 0.f;
        #pragma unroll
        for (int j = 0; j < 12; j += 2) {
          s0 += ex2(x[j] - mx); s1 += ex2(x[j + 1] - mx);
        }
        s0 += ex2(x[12] - mx);
        float s = s0 + s1;
        s += __shfl_xor(s, 1);
        s += __shfl_xor(s, 2);
        if (sub == 0) g2[r] = LOG2_50 - mx - lg2(s);
      }
      __syncthreads();
    }

    float acc = 0.f;
    if (t < NR) acc = f2[t] + g2[t];
    #pragma unroll
    for (int off = 32; off; off >>= 1) acc += __shfl_xor(acc, off);
    if ((t & 63) == 0) red[t >> 6] = acc;
    __syncthreads();
    if (t == 0) ott[p] = VSCALE * (1.0f / NR) * (red[0] + red[1] + red[2] + red[3]);

  } else {
    // ------------------------------ aa body, 256-thread reshape
    // 2 threads/row (r=t>>1, sub=t&1), 16 quads: cols 8q+4sub..+3.
    // No x-cache (keeps VGPR ~90 so ab blocks' occupancy isn't throttled);
    // pass 2 re-reads potentials from LDS (broadcast, conflict-free).
    float* pF  = smem;                   // 128
    float* pG  = smem + 128;             // 128
    float* red = smem + 256;             // 4
    int b = blockIdx.x - (SK_AB + SK_TT);
    const int r = t >> 1, sub = t & 1;
    const float* Cr = Caa + (size_t)b * (NL * NL) + (size_t)r * NL;
    const float* lp = lw2 + b * NL;
    f32x4 Cr4[16];                       // la2[col] - C[r][col]
    #pragma unroll
    for (int q = 0; q < 16; ++q) {
      int c0 = q * 8 + sub * 4;
      float4 cv = *(const float4*)(Cr + c0);
      float4 lv = *(const float4*)(lp + c0);
      Cr4[q] = (f32x4){lv.x - cv.x, lv.y - cv.y, lv.z - cv.z, lv.w - cv.w};
    }
    if (t < NL) { pG[t] = 0.f; pF[t] = 0.f; }
    __syncthreads();

    for (int it = 0; it < NITER; ++it) {
      // ---- f = T(g)
      {
        f32x4 m4 = {SENT, SENT, SENT, SENT};
        #pragma unroll
        for (int q = 0; q < 16; ++q)
          m4 = vmax4(m4, *(const f32x4*)(pG + q * 8 + sub * 4) + Cr4[q]);
        float mx = fmaxf(fmaxf(m4[0], m4[1]), fmaxf(m4[2], m4[3]));
        mx = fmaxf(mx, __shfl_xor(mx, 1));
        f32x4 s4 = {0.f, 0.f, 0.f, 0.f};
        #pragma unroll
        for (int q = 0; q < 16; ++q)
          s4 += vexp4(*(const f32x4*)(pG + q * 8 + sub * 4) + Cr4[q] - mx);
        float s = (s4[0] + s4[1]) + (s4[2] + s4[3]);
        s += __shfl_xor(s, 1);
        if (sub == 0) pF[r] = -(mx + lg2(s));
      }
      __syncthreads();
      // ---- g = T(f)
      {
        f32x4 m4 = {SENT, SENT, SENT, SENT};
        #pragma unroll
        for (int q = 0; q < 16; ++q)
          m4 = vmax4(m4, *(const f32x4*)(pF + q * 8 + sub * 4) + Cr4[q]);
        float mx = fmaxf(fmaxf(m4[0], m4[1]), fmaxf(m4[2], m4[3]));
        mx = fmaxf(mx, __shfl_xor(mx, 1));
        f32x4 s4 = {0.f, 0.f, 0.f, 0.f};
        #pragma unroll
        for (int q = 0; q < 16; ++q)
          s4 += vexp4(*(const f32x4*)(pF + q * 8 + sub * 4) + Cr4[q] - mx);
        float s = (s4[0] + s4[1]) + (s4[2] + s4[3]);
        s += __shfl_xor(s, 1);
        if (sub == 0) pG[r] = -(mx + lg2(s));
      }
      __syncthreads();
    }

    float acc = 0.f;
    if (t < NL) acc = weight[b * NL + t] * (pF[t] + pG[t]);
    #pragma unroll
    for (int off = 32; off; off >>= 1) acc += __shfl_xor(acc, off);
    if ((t & 63) == 0) red[t >> 6] = acc;
    __syncthreads();
    if (t == 0) oaa[b] = VSCALE * (red[0] + red[1] + red[2] + red[3]);
  }
}

// ---------------------------------------------------------------- finalize
__global__ void finalize_kernel(const float* __restrict__ oab, const float* __restrict__ oaa,
                                const float* __restrict__ ott, const int* __restrict__ grade,
                                float* __restrict__ out) {
  __shared__ float selft[NK];
  __shared__ float redL[4], redD[4];
  int t = threadIdx.x;
  if (t < NK) selft[t] = ott[t * NK + t];
  __syncthreads();
  float dpart = (t < NK * NK) ? ott[t] : 0.f;
  float lpart = 0.f;
  if (t < NB) {
    int g = grade[t];
    float oa = oaa[t];
    float dpos = oab[t * NK + g] - 0.5f * (oa + selft[g]);
    float s = 0.f;
    #pragma unroll
    for (int k = 0; k < NK; ++k) {
      float dk = oab[t * NK + k] - 0.5f * (oa + selft[k]);
      s += fmaxf(dpos - dk + 10.0f, 0.0f);
    }
    lpart = s - 10.0f;
  }
  #pragma unroll
  for (int off = 32; off; off >>= 1) {
    dpart += __shfl_xor(dpart, off);
    lpart += __shfl_xor(lpart, off);
  }
  if ((t & 63) == 0) { redD[t >> 6] = dpart; redL[t >> 6] = lpart; }
  __syncthreads();
  if (t == 0) {
    float ds = 0.f, ls = 0.f;
    #pragma unroll
    for (int i = 0; i < 4; ++i) { ds += redD[i]; ls += redL[i]; }
    float ss = 0.f;
    #pragma unroll
    for (int k = 0; k < NK; ++k) ss += selft[k];
    float dis = ds - (float)NK * ss;
    out[0] = ls / (float)NB - dis * 0.01f;
  }
}

// ---------------------------------------------------------------- launch
extern "C" void kernel_launch(void* const* d_in, const int* in_sizes, int n_in,
                              void* d_out, int out_size, void* d_ws, size_t ws_size,
                              hipStream_t stream) {
  (void)in_sizes; (void)n_in; (void)out_size; (void)ws_size;
  const float* anchor = (const float*)d_in[0];
  const float* weight = (const float*)d_in[1];
  const float* t0     = (const float*)d_in[2];
  const int*   len    = (const int*)d_in[3];
  const int*   grade  = (const int*)d_in[4];
  float* out = (float*)d_out;

  float* ws  = (float*)d_ws;
  float* Cab = ws;                                    // 819200
  float* Caa = Cab + (size_t)NB * NK * NL * NR;       // 2097152
  float* Ctt = Caa + (size_t)NB * NL * NL;            // 250000
  float* na  = Ctt + (size_t)NK * NK * NR * NR;       // 16384
  float* nt  = na + NB * NL;                          // 500
  float* lw2 = nt + NK * NR;                          // 16384
  float* oab = lw2 + NB * NL;                         // 1280
  float* oaa = oab + NB * NK;                         // 128
  float* ott = oaa + NB;                              // 100

  prep_kernel<<<(NB * NL + NK * NR) / 4, 256, 0, stream>>>(anchor, weight, t0, len, na, nt, lw2);
  cost_all<<<NAB_TILES + NTT_TILES + NB, 512, 0, stream>>>(anchor, t0, na, nt,
                                                           Cab, Ctt, Caa);
  sinkhorn_all<<<SK_AB + SK_TT + NB, 256, 0, stream>>>(Cab, Ctt, Caa, lw2, weight,
                                                       oab, ott, oaa);
  finalize_kernel<<<1, 256, 0, stream>>>(oab, oaa, ott, grade, out);
}